// Round 9
// baseline (707.957 us; speedup 1.0000x reference)
//
#include <hip/hip_runtime.h>

#define D 256
#define BSHIFT 9
#define BROWS 512            // rows per bucket
#define MAXBK 256            // supports n <= 131072
#define PBLK 512             // partition blocks
#define CPASS 16             // cols per gather pass
#define NPASS (D / CPASS)    // 16 passes

typedef __attribute__((ext_vector_type(8))) short bf16x8;
typedef __attribute__((ext_vector_type(4))) float f32x4;
typedef __attribute__((ext_vector_type(4))) unsigned short u16x4;

static __device__ __forceinline__ unsigned short f2bf(float f) {
    unsigned u = __float_as_uint(f);
    u += 0x7FFF + ((u >> 16) & 1);   // round-to-nearest-even
    return (unsigned short)(u >> 16);
}
static __device__ __forceinline__ float bf_lo(unsigned u) {
    return __uint_as_float(u << 16);
}
static __device__ __forceinline__ float bf_hi(unsigned u) {
    return __uint_as_float(u & 0xFFFF0000u);
}

// ---------------------------------------------------------------------------
// pack W (f32 [256][256]) into MFMA fragment order, bf16 (A operand).
// ---------------------------------------------------------------------------
__global__ __launch_bounds__(256) void pack_W(
    const float* __restrict__ W, unsigned short* __restrict__ Wp)
{
    const int t = blockIdx.x * 256 + threadIdx.x;   // 0..8191
    const int lane = t & 63;
    const int nt = (t >> 6) & 15;
    const int kt = t >> 10;
    const int n = nt * 16 + (lane & 15);
    const int k0 = kt * 32 + (lane >> 4) * 8;
#pragma unroll
    for (int j = 0; j < 8; ++j)
        Wp[(size_t)t * 8 + j] = f2bf(W[n * D + k0 + j]);
}

// ---------------------------------------------------------------------------
// h = bf16(x @ W^T + b), MFMA with swapped operands. h stored COLUMN-BLOCKED:
// h_blk[p][row][c] = h[row][p*16+c], p in [0,16) — each 16-col slice is a
// contiguous 3.2 MB region so the gather passes are per-XCD-L2-resident.
// ---------------------------------------------------------------------------
__global__ __launch_bounds__(256) void mfma_linear(
    const float* __restrict__ x, const unsigned short* __restrict__ Wp,
    const float* __restrict__ b, unsigned short* __restrict__ h, int M)
{
    const int lane = threadIdx.x & 63;
    const int wave = threadIdx.x >> 6;
    const int row0 = blockIdx.x * 128 + wave * 32;
    const int arow = lane & 15;
    const int kgrp = lane >> 4;

    f32x4 acc[2][16];
#pragma unroll
    for (int t = 0; t < 2; ++t)
#pragma unroll
        for (int nt = 0; nt < 16; ++nt)
            acc[t][nt] = (f32x4){0.f, 0.f, 0.f, 0.f};

    for (int kt = 0; kt < 8; ++kt) {
        const int k0 = kt * 32 + kgrp * 8;
        bf16x8 a[2];
#pragma unroll
        for (int t = 0; t < 2; ++t) {
            int r = row0 + t * 16 + arow;
            if (r >= M) r = M - 1;
            const f32x4* xp = (const f32x4*)(x + (size_t)r * D + k0);
            const f32x4 lo = __builtin_nontemporal_load(xp);
            const f32x4 hi = __builtin_nontemporal_load(xp + 1);
            a[t][0] = (short)f2bf(lo[0]); a[t][1] = (short)f2bf(lo[1]);
            a[t][2] = (short)f2bf(lo[2]); a[t][3] = (short)f2bf(lo[3]);
            a[t][4] = (short)f2bf(hi[0]); a[t][5] = (short)f2bf(hi[1]);
            a[t][6] = (short)f2bf(hi[2]); a[t][7] = (short)f2bf(hi[3]);
        }
        const bf16x8* __restrict__ wp =
            (const bf16x8*)Wp + (size_t)(kt * 16) * 64 + lane;
#pragma unroll
        for (int nt = 0; nt < 16; ++nt) {
            const bf16x8 bf = wp[nt * 64];
            acc[0][nt] = __builtin_amdgcn_mfma_f32_16x16x32_bf16(bf, a[0], acc[0][nt], 0, 0, 0);
            acc[1][nt] = __builtin_amdgcn_mfma_f32_16x16x32_bf16(bf, a[1], acc[1][nt], 0, 0, 0);
        }
    }

    // D layout (swapped): xrow = lane&15, wcol = nt*16 + (lane>>4)*4 + reg
    const int srow = lane & 15;
    const int scol0 = (lane >> 4) * 4;
#pragma unroll
    for (int t = 0; t < 2; ++t) {
        const int xrow = row0 + t * 16 + srow;
        if (xrow >= M) continue;
#pragma unroll
        for (int nt = 0; nt < 16; ++nt) {
            const f32x4 bv = *(const f32x4*)(b + nt * 16 + scol0);
            u16x4 st;
            st[0] = f2bf(acc[t][nt][0] + bv[0]);
            st[1] = f2bf(acc[t][nt][1] + bv[1]);
            st[2] = f2bf(acc[t][nt][2] + bv[2]);
            st[3] = f2bf(acc[t][nt][3] + bv[3]);
            // blocked: block nt, row xrow, cols scol0..scol0+3
            *(u16x4*)(h + (size_t)nt * M * CPASS + (size_t)xrow * CPASS + scol0) = st;
        }
    }
}

// ---------------------------------------------------------------------------
// K3: per-block bucket histogram (LDS only, no global atomics).
// ---------------------------------------------------------------------------
__global__ __launch_bounds__(256) void bucket_count(
    const int* __restrict__ adj_row, int* __restrict__ blk_hist, int E, int nbk)
{
    __shared__ int hist[MAXBK];
    const int tid = threadIdx.x;
    const int chunk = (E + PBLK - 1) / PBLK;
    const int e0 = blockIdx.x * chunk;
    const int e1 = min(e0 + chunk, E);

    for (int k = tid; k < nbk; k += 256) hist[k] = 0;
    __syncthreads();
    for (int i = e0 + tid; i < e1; i += 256)
        atomicAdd(&hist[adj_row[i] >> BSHIFT], 1);
    __syncthreads();
    for (int k = tid; k < nbk; k += 256)
        blk_hist[(size_t)blockIdx.x * nbk + k] = hist[k];
}

// ---------------------------------------------------------------------------
// K4: per bucket k, exclusive-scan blk_hist[:][k]; cnt[k] = total.
// ---------------------------------------------------------------------------
__global__ __launch_bounds__(256) void scan_blk_hist(
    int* __restrict__ blk_hist, int* __restrict__ cnt, int nbk)
{
    __shared__ int wsums[4];
    const int k = blockIdx.x;
    const int tid = threadIdx.x;
    const int lane = tid & 63;
    const int wid = tid >> 6;

    const int i0 = 2 * tid, i1 = 2 * tid + 1;
    const int h0 = blk_hist[(size_t)i0 * nbk + k];
    const int h1 = blk_hist[(size_t)i1 * nbk + k];
    const int tsum = h0 + h1;

    int v = tsum;
    for (int d = 1; d < 64; d <<= 1) {
        int u = __shfl_up(v, d, 64);
        if (lane >= d) v += u;
    }
    if (lane == 63) wsums[wid] = v;
    __syncthreads();
    int woff = 0;
    for (int w = 0; w < wid; ++w) woff += wsums[w];
    const int pref = woff + v - tsum;

    blk_hist[(size_t)i0 * nbk + k] = pref;
    blk_hist[(size_t)i1 * nbk + k] = pref + h0;
    if (tid == 0) cnt[k] = wsums[0] + wsums[1] + wsums[2] + wsums[3];
}

// ---------------------------------------------------------------------------
// K5: exclusive scan of cnt -> bbase. Single block, nbk <= 256.
// ---------------------------------------------------------------------------
__global__ __launch_bounds__(256) void scan_cnt(
    const int* __restrict__ cnt, int* __restrict__ bbase, int nbk)
{
    __shared__ int wsums[4];
    const int tid = threadIdx.x;
    const int lane = tid & 63;
    const int wid = tid >> 6;
    const int val = (tid < nbk) ? cnt[tid] : 0;

    int v = val;
    for (int d = 1; d < 64; d <<= 1) {
        int u = __shfl_up(v, d, 64);
        if (lane >= d) v += u;
    }
    if (lane == 63) wsums[wid] = v;
    __syncthreads();
    int woff = 0;
    for (int w = 0; w < wid; ++w) woff += wsums[w];
    if (tid < nbk) bbase[tid] = woff + v - val;
}

// ---------------------------------------------------------------------------
// K6: partition edges into bucket-grouped part[] with precomputed bases.
// part.x = (localrow << 17) | col ; part.y = val quantized to 15-bit fixed.
// ---------------------------------------------------------------------------
__global__ __launch_bounds__(256) void partition_edges(
    const int* __restrict__ adj_row, const int* __restrict__ adj_col,
    const float* __restrict__ adj_vals, const int* __restrict__ bbase,
    const int* __restrict__ blk_hist, uint2* __restrict__ part, int E, int nbk)
{
    __shared__ int sbase[MAXBK];
    __shared__ int lcur[MAXBK];

    const int tid = threadIdx.x;
    const int blk = blockIdx.x;
    const int chunk = (E + PBLK - 1) / PBLK;
    const int e0 = blk * chunk;
    const int e1 = min(e0 + chunk, E);

    for (int k = tid; k < nbk; k += 256) {
        sbase[k] = bbase[k] + blk_hist[(size_t)blk * nbk + k];
        lcur[k] = 0;
    }
    __syncthreads();

    for (int i = e0 + tid; i < e1; i += 256) {
        const int r = adj_row[i];
        const int k = r >> BSHIFT;
        const int col = __builtin_nontemporal_load(adj_col + i);
        const float val = __builtin_nontemporal_load(adj_vals + i);
        const unsigned v15 = (unsigned)(val * 32767.0f + 0.5f);  // val in [0,1)
        const int pos = sbase[k] + atomicAdd(&lcur[k], 1);
        part[pos] = make_uint2(((unsigned)(r & (BROWS - 1)) << 17) | (unsigned)col, v15);
    }
}

// ---------------------------------------------------------------------------
// K7: one block per bucket: local histogram + LDS scan -> row_ptr, then
// scatter part -> csr4 (packed: val15<<17 | col) via LDS cursors.
// ---------------------------------------------------------------------------
__global__ __launch_bounds__(256) void bucket_fill(
    const uint2* __restrict__ part, const int* __restrict__ bbase,
    int* __restrict__ row_ptr, unsigned* __restrict__ csr4, int n, int E, int nbk)
{
    __shared__ int hist[BROWS];
    __shared__ int off[BROWS];
    __shared__ int wsums[4];

    const int tid = threadIdx.x;
    const int lane = tid & 63;
    const int wid = tid >> 6;
    const int bk = blockIdx.x;
    const int row0 = bk << BSHIFT;
    const int nr = min(row0 + BROWS, n) - row0;
    const int base = bbase[bk];
    const int ecnt = ((bk + 1 < nbk) ? bbase[bk + 1] : E) - base;

    for (int r = tid; r < BROWS; r += 256) hist[r] = 0;
    __syncthreads();
    for (int i = tid; i < ecnt; i += 256)
        atomicAdd(&hist[part[base + i].x >> 17], 1);
    __syncthreads();

    const int h0 = hist[2 * tid], h1 = hist[2 * tid + 1];
    const int tsum = h0 + h1;
    int v = tsum;
    for (int d = 1; d < 64; d <<= 1) {
        int u = __shfl_up(v, d, 64);
        if (lane >= d) v += u;
    }
    if (lane == 63) wsums[wid] = v;
    __syncthreads();
    int woff = 0;
    for (int w = 0; w < wid; ++w) woff += wsums[w];
    const int pref = woff + v - tsum;
    off[2 * tid] = pref;
    off[2 * tid + 1] = pref + h0;
    __syncthreads();

    for (int r = tid; r < nr; r += 256) row_ptr[row0 + r] = base + off[r];
    if (bk == nbk - 1 && tid == 0) row_ptr[n] = E;
    for (int r = tid; r < BROWS; r += 256) hist[r] = base + off[r];
    __syncthreads();

    for (int i = tid; i < ecnt; i += 256) {
        const uint2 w = part[base + i];
        const int lr = w.x >> 17;
        const int pos = atomicAdd(&hist[lr], 1);
        csr4[pos] = (w.y << 17) | (w.x & 0x1FFFF);
    }
}

// ---------------------------------------------------------------------------
// K8: 16-pass gather over column-blocked bf16 h + fused ReLU.
// Grid is pass-major (bid = pass*NRB + rb) so in-flight blocks share one
// 3.2 MB h slice -> per-XCD-L2-resident. Wave = 2 rows; per row-half:
// 8 edge slots x 4 uint2 lanes (16 cols); shfl_xor(4/8/16) reduce.
// ---------------------------------------------------------------------------
__global__ __launch_bounds__(256) void gather_pass(
    const int* __restrict__ row_ptr, const unsigned* __restrict__ csr4,
    const unsigned short* __restrict__ h, float* __restrict__ out, int n, int nrb)
{
    const int pass = blockIdx.x / nrb;
    const int rb   = blockIdx.x % nrb;
    const int wave = threadIdx.x >> 6;
    const int lane = threadIdx.x & 63;
    const int rhalf = lane >> 5;         // which of the wave's 2 rows
    const int l32 = lane & 31;
    const int e = l32 >> 2;              // edge slot 0..7
    const int c2 = l32 & 3;              // uint2 slot (4 cols)

    const int row = rb * 8 + wave * 2 + rhalf;
    if (row >= n) return;

    const int s = row_ptr[row];
    const int eend = row_ptr[row + 1];

    const unsigned* __restrict__ hp =
        (const unsigned*)h + (size_t)pass * n * (CPASS / 2);

    float a0 = 0.f, a1 = 0.f, a2 = 0.f, a3 = 0.f;

    for (int i = s; i < eend; i += 8) {
        const int idx = i + e;
        const unsigned w = (idx < eend) ? __builtin_nontemporal_load(csr4 + idx) : 0u;
        const unsigned col = w & 0x1FFFFu;
        const float val = (float)(w >> 17) * (1.0f / 32767.0f);
        const uint2 d = *(const uint2*)(hp + (size_t)col * (CPASS / 2) + c2 * 2);
        a0 += val * bf_lo(d.x);
        a1 += val * bf_hi(d.x);
        a2 += val * bf_lo(d.y);
        a3 += val * bf_hi(d.y);
    }

    // reduce over edge slots (lane bits 2,3,4) — stays within the 32-half
#pragma unroll
    for (int dlt = 4; dlt <= 16; dlt <<= 1) {
        a0 += __shfl_xor(a0, dlt, 64);
        a1 += __shfl_xor(a1, dlt, 64);
        a2 += __shfl_xor(a2, dlt, 64);
        a3 += __shfl_xor(a3, dlt, 64);
    }

    if (e == 0) {
        f32x4 st;
        st[0] = fmaxf(a0, 0.f); st[1] = fmaxf(a1, 0.f);
        st[2] = fmaxf(a2, 0.f); st[3] = fmaxf(a3, 0.f);
        __builtin_nontemporal_store(st,
            (f32x4*)(out + (size_t)row * D + pass * CPASS + c2 * 4));
    }
}

// ---------------------------------------------------------------------------
extern "C" void kernel_launch(void* const* d_in, const int* in_sizes, int n_in,
                              void* d_out, int out_size, void* d_ws, size_t ws_size,
                              hipStream_t stream)
{
    const float* x        = (const float*)d_in[0];
    const int*   adj_row  = (const int*)d_in[1];
    const int*   adj_col  = (const int*)d_in[2];
    const float* adj_vals = (const float*)d_in[3];
    const float* W        = (const float*)d_in[4];
    const float* b        = (const float*)d_in[5];
    float*       out      = (float*)d_out;

    const int n = in_sizes[0] / D;               // 100000 nodes
    const int E = in_sizes[1];                   // 3.2M edges
    const int nbk = (n + BROWS - 1) >> BSHIFT;   // buckets (196)

    char* ws = (char*)d_ws;
    size_t off = 0;
    auto alloc = [&](size_t bytes) {
        size_t o = off;
        off += (bytes + 255) & ~(size_t)255;
        return o;
    };
    unsigned short* h  = (unsigned short*)(ws + alloc((size_t)n * D * sizeof(unsigned short)));
    unsigned short* Wp = (unsigned short*)(ws + alloc((size_t)8192 * 8 * sizeof(unsigned short)));
    int*      blk_hist = (int*)     (ws + alloc((size_t)PBLK * nbk * sizeof(int)));
    int*      cnt      = (int*)     (ws + alloc((size_t)MAXBK * sizeof(int)));
    int*      bbase    = (int*)     (ws + alloc((size_t)MAXBK * sizeof(int)));
    int*      row_ptr  = (int*)     (ws + alloc((size_t)(n + 1) * sizeof(int)));
    uint2*    part     = (uint2*)   (ws + alloc((size_t)E * sizeof(uint2)));
    unsigned* csr4     = (unsigned*)(ws + alloc((size_t)E * sizeof(unsigned)));
    (void)ws_size;

    // linear (writes column-blocked h)
    pack_W<<<32, 256, 0, stream>>>(W, Wp);
    mfma_linear<<<(n + 127) / 128, 256, 0, stream>>>(x, Wp, b, h, n);

    // CSR build — atomic-free (LDS histograms + deterministic scans)
    bucket_count<<<PBLK, 256, 0, stream>>>(adj_row, blk_hist, E, nbk);
    scan_blk_hist<<<nbk, 256, 0, stream>>>(blk_hist, cnt, nbk);
    scan_cnt<<<1, 256, 0, stream>>>(cnt, bbase, nbk);
    partition_edges<<<PBLK, 256, 0, stream>>>(adj_row, adj_col, adj_vals, bbase, blk_hist, part, E, nbk);
    bucket_fill<<<nbk, 256, 0, stream>>>(part, bbase, row_ptr, csr4, n, E, nbk);

    // 16-pass gather + ReLU (pass-major grid for L2-resident h slices)
    const int nrb = (n + 7) / 8;
    gather_pass<<<NPASS * nrb, 256, 0, stream>>>(row_ptr, csr4, h, out, n, nrb);
}

// Round 10
// 455.075 us; speedup vs baseline: 1.5557x; 1.5557x over previous
//
#include <hip/hip_runtime.h>

#define D 256
#define BSHIFT 9
#define BROWS 512            // rows per bucket
#define MAXBK 256            // supports n <= 131072
#define PBLK 512             // partition blocks
#define CPASS 16             // cols per gather pass
#define NPASS (D / CPASS)    // 16 passes

typedef __attribute__((ext_vector_type(8))) short bf16x8;
typedef __attribute__((ext_vector_type(4))) float f32x4;
typedef __attribute__((ext_vector_type(4))) unsigned short u16x4;

static __device__ __forceinline__ unsigned short f2bf(float f) {
    unsigned u = __float_as_uint(f);
    u += 0x7FFF + ((u >> 16) & 1);   // round-to-nearest-even
    return (unsigned short)(u >> 16);
}
static __device__ __forceinline__ float bf_lo(unsigned u) {
    return __uint_as_float(u << 16);
}
static __device__ __forceinline__ float bf_hi(unsigned u) {
    return __uint_as_float(u & 0xFFFF0000u);
}

// ---------------------------------------------------------------------------
// pack W (f32 [256][256]) into MFMA fragment order, bf16 (A operand).
// ---------------------------------------------------------------------------
__global__ __launch_bounds__(256) void pack_W(
    const float* __restrict__ W, unsigned short* __restrict__ Wp)
{
    const int t = blockIdx.x * 256 + threadIdx.x;   // 0..8191
    const int lane = t & 63;
    const int nt = (t >> 6) & 15;
    const int kt = t >> 10;
    const int n = nt * 16 + (lane & 15);
    const int k0 = kt * 32 + (lane >> 4) * 8;
#pragma unroll
    for (int j = 0; j < 8; ++j)
        Wp[(size_t)t * 8 + j] = f2bf(W[n * D + k0 + j]);
}

// ---------------------------------------------------------------------------
// h = bf16(x @ W^T + b), MFMA swapped operands, h stored COLUMN-BLOCKED:
// h_blk[p][row][c] = h[row][p*16+c]  (16-col slice = contiguous 3.2 MB).
// ---------------------------------------------------------------------------
__global__ __launch_bounds__(256) void mfma_linear(
    const float* __restrict__ x, const unsigned short* __restrict__ Wp,
    const float* __restrict__ b, unsigned short* __restrict__ h, int M)
{
    const int lane = threadIdx.x & 63;
    const int wave = threadIdx.x >> 6;
    const int row0 = blockIdx.x * 128 + wave * 32;
    const int arow = lane & 15;
    const int kgrp = lane >> 4;

    f32x4 acc[2][16];
#pragma unroll
    for (int t = 0; t < 2; ++t)
#pragma unroll
        for (int nt = 0; nt < 16; ++nt)
            acc[t][nt] = (f32x4){0.f, 0.f, 0.f, 0.f};

    for (int kt = 0; kt < 8; ++kt) {
        const int k0 = kt * 32 + kgrp * 8;
        bf16x8 a[2];
#pragma unroll
        for (int t = 0; t < 2; ++t) {
            int r = row0 + t * 16 + arow;
            if (r >= M) r = M - 1;
            const f32x4* xp = (const f32x4*)(x + (size_t)r * D + k0);
            const f32x4 lo = __builtin_nontemporal_load(xp);
            const f32x4 hi = __builtin_nontemporal_load(xp + 1);
            a[t][0] = (short)f2bf(lo[0]); a[t][1] = (short)f2bf(lo[1]);
            a[t][2] = (short)f2bf(lo[2]); a[t][3] = (short)f2bf(lo[3]);
            a[t][4] = (short)f2bf(hi[0]); a[t][5] = (short)f2bf(hi[1]);
            a[t][6] = (short)f2bf(hi[2]); a[t][7] = (short)f2bf(hi[3]);
        }
        const bf16x8* __restrict__ wp =
            (const bf16x8*)Wp + (size_t)(kt * 16) * 64 + lane;
#pragma unroll
        for (int nt = 0; nt < 16; ++nt) {
            const bf16x8 bf = wp[nt * 64];
            acc[0][nt] = __builtin_amdgcn_mfma_f32_16x16x32_bf16(bf, a[0], acc[0][nt], 0, 0, 0);
            acc[1][nt] = __builtin_amdgcn_mfma_f32_16x16x32_bf16(bf, a[1], acc[1][nt], 0, 0, 0);
        }
    }

    const int srow = lane & 15;
    const int scol0 = (lane >> 4) * 4;
#pragma unroll
    for (int t = 0; t < 2; ++t) {
        const int xrow = row0 + t * 16 + srow;
        if (xrow >= M) continue;
#pragma unroll
        for (int nt = 0; nt < 16; ++nt) {
            const f32x4 bv = *(const f32x4*)(b + nt * 16 + scol0);
            u16x4 st;
            st[0] = f2bf(acc[t][nt][0] + bv[0]);
            st[1] = f2bf(acc[t][nt][1] + bv[1]);
            st[2] = f2bf(acc[t][nt][2] + bv[2]);
            st[3] = f2bf(acc[t][nt][3] + bv[3]);
            *(u16x4*)(h + (size_t)nt * M * CPASS + (size_t)xrow * CPASS + scol0) = st;
        }
    }
}

// ---------------------------------------------------------------------------
// CSR build (atomic-free): per-block bucket histograms -> scans -> partition
// -> per-bucket fill.  csr4 entry = val15 << 17 | col.
// ---------------------------------------------------------------------------
__global__ __launch_bounds__(256) void bucket_count(
    const int* __restrict__ adj_row, int* __restrict__ blk_hist, int E, int nbk)
{
    __shared__ int hist[MAXBK];
    const int tid = threadIdx.x;
    const int chunk = (E + PBLK - 1) / PBLK;
    const int e0 = blockIdx.x * chunk;
    const int e1 = min(e0 + chunk, E);

    for (int k = tid; k < nbk; k += 256) hist[k] = 0;
    __syncthreads();
    for (int i = e0 + tid; i < e1; i += 256)
        atomicAdd(&hist[adj_row[i] >> BSHIFT], 1);
    __syncthreads();
    for (int k = tid; k < nbk; k += 256)
        blk_hist[(size_t)blockIdx.x * nbk + k] = hist[k];
}

__global__ __launch_bounds__(256) void scan_blk_hist(
    int* __restrict__ blk_hist, int* __restrict__ cnt, int nbk)
{
    __shared__ int wsums[4];
    const int k = blockIdx.x;
    const int tid = threadIdx.x;
    const int lane = tid & 63;
    const int wid = tid >> 6;

    const int i0 = 2 * tid, i1 = 2 * tid + 1;
    const int h0 = blk_hist[(size_t)i0 * nbk + k];
    const int h1 = blk_hist[(size_t)i1 * nbk + k];
    const int tsum = h0 + h1;

    int v = tsum;
    for (int d = 1; d < 64; d <<= 1) {
        int u = __shfl_up(v, d, 64);
        if (lane >= d) v += u;
    }
    if (lane == 63) wsums[wid] = v;
    __syncthreads();
    int woff = 0;
    for (int w = 0; w < wid; ++w) woff += wsums[w];
    const int pref = woff + v - tsum;

    blk_hist[(size_t)i0 * nbk + k] = pref;
    blk_hist[(size_t)i1 * nbk + k] = pref + h0;
    if (tid == 0) cnt[k] = wsums[0] + wsums[1] + wsums[2] + wsums[3];
}

__global__ __launch_bounds__(256) void scan_cnt(
    const int* __restrict__ cnt, int* __restrict__ bbase, int nbk)
{
    __shared__ int wsums[4];
    const int tid = threadIdx.x;
    const int lane = tid & 63;
    const int wid = tid >> 6;
    const int val = (tid < nbk) ? cnt[tid] : 0;

    int v = val;
    for (int d = 1; d < 64; d <<= 1) {
        int u = __shfl_up(v, d, 64);
        if (lane >= d) v += u;
    }
    if (lane == 63) wsums[wid] = v;
    __syncthreads();
    int woff = 0;
    for (int w = 0; w < wid; ++w) woff += wsums[w];
    if (tid < nbk) bbase[tid] = woff + v - val;
}

__global__ __launch_bounds__(256) void partition_edges(
    const int* __restrict__ adj_row, const int* __restrict__ adj_col,
    const float* __restrict__ adj_vals, const int* __restrict__ bbase,
    const int* __restrict__ blk_hist, uint2* __restrict__ part, int E, int nbk)
{
    __shared__ int sbase[MAXBK];
    __shared__ int lcur[MAXBK];

    const int tid = threadIdx.x;
    const int blk = blockIdx.x;
    const int chunk = (E + PBLK - 1) / PBLK;
    const int e0 = blk * chunk;
    const int e1 = min(e0 + chunk, E);

    for (int k = tid; k < nbk; k += 256) {
        sbase[k] = bbase[k] + blk_hist[(size_t)blk * nbk + k];
        lcur[k] = 0;
    }
    __syncthreads();

    for (int i = e0 + tid; i < e1; i += 256) {
        const int r = adj_row[i];
        const int k = r >> BSHIFT;
        const int col = __builtin_nontemporal_load(adj_col + i);
        const float val = __builtin_nontemporal_load(adj_vals + i);
        const unsigned v15 = (unsigned)(val * 32767.0f + 0.5f);  // val in [0,1)
        const int pos = sbase[k] + atomicAdd(&lcur[k], 1);
        part[pos] = make_uint2(((unsigned)(r & (BROWS - 1)) << 17) | (unsigned)col, v15);
    }
}

__global__ __launch_bounds__(256) void bucket_fill(
    const uint2* __restrict__ part, const int* __restrict__ bbase,
    int* __restrict__ row_ptr, unsigned* __restrict__ csr4, int n, int E, int nbk)
{
    __shared__ int hist[BROWS];
    __shared__ int off[BROWS];
    __shared__ int wsums[4];

    const int tid = threadIdx.x;
    const int lane = tid & 63;
    const int wid = tid >> 6;
    const int bk = blockIdx.x;
    const int row0 = bk << BSHIFT;
    const int nr = min(row0 + BROWS, n) - row0;
    const int base = bbase[bk];
    const int ecnt = ((bk + 1 < nbk) ? bbase[bk + 1] : E) - base;

    for (int r = tid; r < BROWS; r += 256) hist[r] = 0;
    __syncthreads();
    for (int i = tid; i < ecnt; i += 256)
        atomicAdd(&hist[part[base + i].x >> 17], 1);
    __syncthreads();

    const int h0 = hist[2 * tid], h1 = hist[2 * tid + 1];
    const int tsum = h0 + h1;
    int v = tsum;
    for (int d = 1; d < 64; d <<= 1) {
        int u = __shfl_up(v, d, 64);
        if (lane >= d) v += u;
    }
    if (lane == 63) wsums[wid] = v;
    __syncthreads();
    int woff = 0;
    for (int w = 0; w < wid; ++w) woff += wsums[w];
    const int pref = woff + v - tsum;
    off[2 * tid] = pref;
    off[2 * tid + 1] = pref + h0;
    __syncthreads();

    for (int r = tid; r < nr; r += 256) row_ptr[row0 + r] = base + off[r];
    if (bk == nbk - 1 && tid == 0) row_ptr[n] = E;
    for (int r = tid; r < BROWS; r += 256) hist[r] = base + off[r];
    __syncthreads();

    for (int i = tid; i < ecnt; i += 256) {
        const uint2 w = part[base + i];
        const int lr = w.x >> 17;
        const int pos = atomicAdd(&hist[lr], 1);
        csr4[pos] = (w.y << 17) | (w.x & 0x1FFFF);
    }
}

// ---------------------------------------------------------------------------
// K8: 16-pass gather, MLP-oriented. Pass-major grid (bid = pass*nrb + rb).
// Block = 16 rows; 16 lanes per row = 8 edge-slots x 2 col-halves; each lane
// loads 16 B (8 cols) per edge. Inner loop unrolled 2x with all loads issued
// before use -> ~16 h-lines in flight per row group. 3 shfl_xor rounds.
// ---------------------------------------------------------------------------
__global__ __launch_bounds__(256) void gather_pass16(
    const int* __restrict__ row_ptr, const unsigned* __restrict__ csr4,
    const unsigned short* __restrict__ h, float* __restrict__ out, int n, int nrb)
{
    const int pass = blockIdx.x / nrb;
    const int rb   = blockIdx.x % nrb;
    const int tid  = threadIdx.x;
    const int rgrp = tid >> 4;          // 0..15 rows per block
    const int l16  = tid & 15;
    const int slot = l16 >> 1;          // 0..7
    const int half = l16 & 1;           // 0..1 (8 cols each)

    const int row = rb * 16 + rgrp;
    if (row >= n) return;

    const int s = row_ptr[row];
    const int eend = row_ptr[row + 1];

    const unsigned short* __restrict__ hp =
        h + (size_t)pass * n * CPASS + half * 8;

    float a0 = 0.f, a1 = 0.f, a2 = 0.f, a3 = 0.f;
    float a4 = 0.f, a5 = 0.f, a6 = 0.f, a7 = 0.f;

    for (int i = s + slot; i < eend; i += 16) {
        const int i1 = i + 8;
        const bool ok1 = i1 < eend;
        // issue both csr loads, then both h loads, before any math
        const unsigned w0 = csr4[i];
        const unsigned w1 = ok1 ? csr4[i1] : 0u;
        const uint4 d0 = *(const uint4*)(hp + (size_t)(w0 & 0x1FFFFu) * CPASS);
        const uint4 d1 = *(const uint4*)(hp + (size_t)(w1 & 0x1FFFFu) * CPASS);
        const float v0 = (float)(w0 >> 17) * (1.0f / 32767.0f);
        const float v1 = ok1 ? (float)(w1 >> 17) * (1.0f / 32767.0f) : 0.f;

        a0 += v0 * bf_lo(d0.x) + v1 * bf_lo(d1.x);
        a1 += v0 * bf_hi(d0.x) + v1 * bf_hi(d1.x);
        a2 += v0 * bf_lo(d0.y) + v1 * bf_lo(d1.y);
        a3 += v0 * bf_hi(d0.y) + v1 * bf_hi(d1.y);
        a4 += v0 * bf_lo(d0.z) + v1 * bf_lo(d1.z);
        a5 += v0 * bf_hi(d0.z) + v1 * bf_hi(d1.z);
        a6 += v0 * bf_lo(d0.w) + v1 * bf_lo(d1.w);
        a7 += v0 * bf_hi(d0.w) + v1 * bf_hi(d1.w);
    }

    // reduce over the 8 edge-slots (lane bits 1..3)
#pragma unroll
    for (int dlt = 2; dlt <= 8; dlt <<= 1) {
        a0 += __shfl_xor(a0, dlt, 64);
        a1 += __shfl_xor(a1, dlt, 64);
        a2 += __shfl_xor(a2, dlt, 64);
        a3 += __shfl_xor(a3, dlt, 64);
        a4 += __shfl_xor(a4, dlt, 64);
        a5 += __shfl_xor(a5, dlt, 64);
        a6 += __shfl_xor(a6, dlt, 64);
        a7 += __shfl_xor(a7, dlt, 64);
    }

    if (slot == 0) {
        float* op = out + (size_t)row * D + pass * CPASS + half * 8;
        f32x4 s0, s1;
        s0[0] = fmaxf(a0, 0.f); s0[1] = fmaxf(a1, 0.f);
        s0[2] = fmaxf(a2, 0.f); s0[3] = fmaxf(a3, 0.f);
        s1[0] = fmaxf(a4, 0.f); s1[1] = fmaxf(a5, 0.f);
        s1[2] = fmaxf(a6, 0.f); s1[3] = fmaxf(a7, 0.f);
        *(f32x4*)op = s0;
        *(f32x4*)(op + 4) = s1;
    }
}

// ---------------------------------------------------------------------------
extern "C" void kernel_launch(void* const* d_in, const int* in_sizes, int n_in,
                              void* d_out, int out_size, void* d_ws, size_t ws_size,
                              hipStream_t stream)
{
    const float* x        = (const float*)d_in[0];
    const int*   adj_row  = (const int*)d_in[1];
    const int*   adj_col  = (const int*)d_in[2];
    const float* adj_vals = (const float*)d_in[3];
    const float* W        = (const float*)d_in[4];
    const float* b        = (const float*)d_in[5];
    float*       out      = (float*)d_out;

    const int n = in_sizes[0] / D;               // 100000 nodes
    const int E = in_sizes[1];                   // 3.2M edges
    const int nbk = (n + BROWS - 1) >> BSHIFT;   // buckets (196)

    char* ws = (char*)d_ws;
    size_t off = 0;
    auto alloc = [&](size_t bytes) {
        size_t o = off;
        off += (bytes + 255) & ~(size_t)255;
        return o;
    };
    unsigned short* h  = (unsigned short*)(ws + alloc((size_t)n * D * sizeof(unsigned short)));
    unsigned short* Wp = (unsigned short*)(ws + alloc((size_t)8192 * 8 * sizeof(unsigned short)));
    int*      blk_hist = (int*)     (ws + alloc((size_t)PBLK * nbk * sizeof(int)));
    int*      cnt      = (int*)     (ws + alloc((size_t)MAXBK * sizeof(int)));
    int*      bbase    = (int*)     (ws + alloc((size_t)MAXBK * sizeof(int)));
    int*      row_ptr  = (int*)     (ws + alloc((size_t)(n + 1) * sizeof(int)));
    uint2*    part     = (uint2*)   (ws + alloc((size_t)E * sizeof(uint2)));
    unsigned* csr4     = (unsigned*)(ws + alloc((size_t)E * sizeof(unsigned)));
    (void)ws_size;

    // linear (writes column-blocked h)
    pack_W<<<32, 256, 0, stream>>>(W, Wp);
    mfma_linear<<<(n + 127) / 128, 256, 0, stream>>>(x, Wp, b, h, n);

    // CSR build — atomic-free
    bucket_count<<<PBLK, 256, 0, stream>>>(adj_row, blk_hist, E, nbk);
    scan_blk_hist<<<nbk, 256, 0, stream>>>(blk_hist, cnt, nbk);
    scan_cnt<<<1, 256, 0, stream>>>(cnt, bbase, nbk);
    partition_edges<<<PBLK, 256, 0, stream>>>(adj_row, adj_col, adj_vals, bbase, blk_hist, part, E, nbk);
    bucket_fill<<<nbk, 256, 0, stream>>>(part, bbase, row_ptr, csr4, n, E, nbk);

    // 16-pass gather + ReLU (pass-major grid, MLP-unrolled)
    const int nrb = (n + 15) / 16;
    gather_pass16<<<NPASS * nrb, 256, 0, stream>>>(row_ptr, csr4, h, out, n, nrb);
}